// Round 8
// baseline (241.850 us; speedup 1.0000x reference)
//
#include <hip/hip_runtime.h>
#include <hip/hip_bf16.h>

#define DM 1024
#define NH 16
#define DK 64
#define TT 2048
#define BATCH 2

typedef __attribute__((ext_vector_type(8))) short bf16x8;
typedef __attribute__((ext_vector_type(4))) float f32x4;
typedef __attribute__((ext_vector_type(4))) unsigned short u16x4;
typedef unsigned short u16;

__device__ inline u16 f2b(float x){ __hip_bfloat16 h = __float2bfloat16(x); return *reinterpret_cast<u16*>(&h); }

__device__ inline void gl_lds16(const u16* g, u16* l) {
  __builtin_amdgcn_global_load_lds(
      (const __attribute__((address_space(1))) unsigned int*)g,
      (__attribute__((address_space(3))) unsigned int*)l, 16, 0, 0);
}

// ---------- prep: fused fp32->bf16 activation convert (z<3) + weight transpose (z>=3) ----------
__global__ __launch_bounds__(256) void prep(const float* __restrict__ q, const float* __restrict__ k,
                                            const float* __restrict__ v,
                                            const float* __restrict__ wq, const float* __restrict__ wk,
                                            const float* __restrict__ wv, const float* __restrict__ wo,
                                            u16* __restrict__ qb, u16* __restrict__ kb,
                                            u16* __restrict__ vb, u16* __restrict__ wt) {
  int z = blockIdx.z;
  if (z < 3) {
    const float* src = z==0 ? q : z==1 ? k : v;
    u16* dst = z==0 ? qb : z==1 ? kb : vb;
    size_t i = ((size_t)blockIdx.x*256 + threadIdx.x)*8;
    f32x4 a = *(const f32x4*)(src+i);
    f32x4 b = *(const f32x4*)(src+i+4);
    union { bf16x8 v8; u16 e[8]; } u;
    #pragma unroll
    for (int j=0;j<4;j++){ u.e[j] = f2b(a[j]); u.e[4+j] = f2b(b[j]); }
    *(bf16x8*)(dst+i) = u.v8;
  } else {
    int bx = blockIdx.x;
    if (bx >= 1024) return;
    __shared__ float tile[32][33];
    const float* src = z==3 ? wq : z==4 ? wk : z==5 ? wv : wo;
    u16* dst = wt + (size_t)(z-3)*DM*DM;
    int bxx = bx & 31, byy = bx >> 5;
    int tx = threadIdx.x & 31, ty = threadIdx.x >> 5;   // 32 x 8
    int x  = bxx*32 + tx;
    int y0 = byy*32 + ty;
    #pragma unroll
    for (int i=0;i<32;i+=8) tile[ty+i][tx] = src[(size_t)(y0+i)*DM + x];
    __syncthreads();
    int xo = byy*32 + tx;
    int yo = bxx*32 + ty;
    #pragma unroll
    for (int i=0;i<32;i+=8) dst[(size_t)(yo+i)*DM + xo] = f2b(tile[tx][ty+i]);
  }
}

// ---------- QKV projection GEMM: R5-measured config — BK=32, single buffers ----------
// mode 0: head-major bf16 out [B,H,T,DK]; mode 1: V-transposed bf16 out [B,H,DK,T].
__global__ __launch_bounds__(256) void gemm_qkv(const u16* __restrict__ qb, const u16* __restrict__ kb,
                                                const u16* __restrict__ vb, const u16* __restrict__ wt,
                                                const float* __restrict__ bq, const float* __restrict__ bk,
                                                const float* __restrict__ bv,
                                                u16* __restrict__ qh, u16* __restrict__ kh,
                                                u16* __restrict__ vhT) {
  const int z = blockIdx.z;
  const u16* A = z==0 ? qb : z==1 ? kb : vb;
  const u16* W = wt + (size_t)z*DM*DM;
  const float* bias = z==0 ? bq : z==1 ? bk : bv;
  u16* outv = z==0 ? qh : z==1 ? kh : vhT;
  const int mode = (z==2) ? 1 : 0;
  const float oscale = (z==0) ? 0.125f : 1.0f;   // fold 1/sqrt(64) into Q

  __shared__ u16 As[128*32];
  __shared__ u16 Bs[128*32];
  const int tid = threadIdx.x, lane = tid & 63, wid = tid >> 6;
  const int li = lane & 15, quad = lane >> 4;
  const int row0 = blockIdx.x*128, col0 = blockIdx.y*128;
  const int wr = wid & 1, wc = wid >> 1;

  f32x4 acc[4][4];
  #pragma unroll
  for (int i=0;i<4;i++)
    #pragma unroll
    for (int j=0;j<4;j++) acc[i][j] = f32x4{0.f,0.f,0.f,0.f};

  const int srow = lane >> 2;        // 0..15
  const int scol = (lane & 3) * 8;   // 0,8,16,24

  for (int k0 = 0; k0 < DM; k0 += 32) {
    #pragma unroll
    for (int c = 0; c < 2; c++) {
      int ch = wid*2 + c;
      gl_lds16(A + (size_t)(row0 + ch*16 + srow)*DM + k0 + scol, As + ch*512);
      gl_lds16(W + (size_t)(col0 + ch*16 + srow)*DM + k0 + scol, Bs + ch*512);
    }
    __syncthreads();
    bf16x8 a[4], b[4];
    #pragma unroll
    for (int i=0;i<4;i++) a[i] = *(const bf16x8*)&As[(wr*64 + i*16 + li)*32 + quad*8];
    #pragma unroll
    for (int j=0;j<4;j++) b[j] = *(const bf16x8*)&Bs[(wc*64 + j*16 + li)*32 + quad*8];
    #pragma unroll
    for (int i=0;i<4;i++)
      #pragma unroll
      for (int j=0;j<4;j++)
        acc[i][j] = __builtin_amdgcn_mfma_f32_16x16x32_bf16(a[i], b[j], acc[i][j], 0,0,0);
    __syncthreads();
  }

  // C layout: col=lane&15, row=quad*4+reg  [m89/m91]
  #pragma unroll
  for (int j=0;j<4;j++) {
    int col = col0 + wc*64 + j*16 + li;
    float bsv = bias[col];
    #pragma unroll
    for (int i=0;i<4;i++) {
      #pragma unroll
      for (int r=0;r<4;r++) {
        int row = row0 + wr*64 + i*16 + quad*4 + r;
        float vv = (acc[i][j][r] + bsv) * oscale;
        int bb = row >> 11, t = row & (TT-1);
        int hh = col >> 6,  d = col & 63;
        size_t idx = (mode == 0)
          ? ((((size_t)(bb*NH + hh)*TT + t) << 6) + d)              // [b,h,t,d]
          : ((((size_t)(bb*NH + hh)*DK + d)*TT) + t);               // [b,h,d,t]
        outv[idx] = f2b(vv);
      }
    }
  }
}

// ---------- output GEMM: 128x64 tiles (512 blocks), 2x BK=32 sub-tiles per round ----------
__global__ __launch_bounds__(256) void gemm_out64(const u16* __restrict__ A, const u16* __restrict__ W,
                                                  const float* __restrict__ bias, float* __restrict__ out) {
  __shared__ u16 As[2][128*32];
  __shared__ u16 Bs[2][64*32];
  const int tid = threadIdx.x, lane = tid & 63, wid = tid >> 6;
  const int li = lane & 15, quad = lane >> 4;
  const int row0 = blockIdx.x*128, col0 = blockIdx.y*64;
  const int wr = wid & 1, wc = wid >> 1;

  f32x4 acc[4][2];
  #pragma unroll
  for (int i=0;i<4;i++)
    #pragma unroll
    for (int j=0;j<2;j++) acc[i][j] = f32x4{0.f,0.f,0.f,0.f};

  const int srow = lane >> 2;
  const int scol = (lane & 3) * 8;

  for (int k0 = 0; k0 < DM; k0 += 64) {
    __syncthreads();
    #pragma unroll
    for (int s=0;s<2;s++) {
      #pragma unroll
      for (int c=0;c<2;c++) {
        int ch = wid*2 + c;
        gl_lds16(A + (size_t)(row0 + ch*16 + srow)*DM + k0 + s*32 + scol, As[s] + ch*512);
      }
      gl_lds16(W + (size_t)(col0 + wid*16 + srow)*DM + k0 + s*32 + scol, Bs[s] + wid*512);
    }
    __syncthreads();
    #pragma unroll
    for (int s=0;s<2;s++) {
      bf16x8 a[4], b[2];
      #pragma unroll
      for (int i=0;i<4;i++) a[i] = *(const bf16x8*)&As[s][(wr*64 + i*16 + li)*32 + quad*8];
      #pragma unroll
      for (int j=0;j<2;j++) b[j] = *(const bf16x8*)&Bs[s][(wc*32 + j*16 + li)*32 + quad*8];
      #pragma unroll
      for (int i=0;i<4;i++)
        #pragma unroll
        for (int j=0;j<2;j++)
          acc[i][j] = __builtin_amdgcn_mfma_f32_16x16x32_bf16(a[i], b[j], acc[i][j], 0,0,0);
    }
  }

  #pragma unroll
  for (int j=0;j<2;j++) {
    int col = col0 + wc*32 + j*16 + li;
    float bsv = bias[col];
    #pragma unroll
    for (int i=0;i<4;i++) {
      #pragma unroll
      for (int r=0;r<4;r++) {
        int row = row0 + wr*64 + i*16 + quad*4 + r;
        out[(size_t)row*DM + col] = acc[i][j][r] + bsv;
      }
    }
  }
}

// ---------- flash v6: single-barrier ping-pong K/V staging, flattened 33-iter loop ----------
// Block = (bh, pair pr): q-tiles pr then 31-pr. One __syncthreads per key-tile:
// sync -> compute buf[cur] -> write buf[cur^1] (regs prefetched last iter) -> issue next loads.
// Safety: top-of-iter sync means every wave finished iter g-1 entirely, so no wave still
// reads buf[cur^1] when it is overwritten.
__global__ __launch_bounds__(256) void flash(const u16* __restrict__ qh, const u16* __restrict__ kh,
                                             const u16* __restrict__ vhT, u16* __restrict__ ctx) {
  const int bh = blockIdx.x;
  const int pr = blockIdx.y;                   // pair index 0..15
  const int b = bh >> 4, h = bh & 15;
  const u16* Q  = qh  + (size_t)bh*TT*DK;
  const u16* K  = kh  + (size_t)bh*TT*DK;
  const u16* Vt = vhT + (size_t)bh*DK*TT;      // [d][t]

  const int tid = threadIdx.x, lane = tid & 63, wid = tid >> 6;
  const int li = lane & 15, quad = lane >> 4;

  __shared__ u16 Kl[2][64][72];
  __shared__ u16 Vl[2][64][72];
  __shared__ u16 Pb[4][16][72];

  const int sr = tid >> 3;          // 0..31
  const int sc = (tid & 7) * 8;     // 0..56

  const int ntA = pr + 1;           // phase-A key tiles; total tiles = 33
  const int qrA = pr*64 + wid*16;
  const int qrB = (31-pr)*64 + wid*16;

  // preload Q fragments for both phases (B-operand: n=q at lane li)
  bf16x8 qfA0 = *(const bf16x8*)&Q[(size_t)(qrA+li)*DK +      quad*8];
  bf16x8 qfA1 = *(const bf16x8*)&Q[(size_t)(qrA+li)*DK + 32 + quad*8];
  bf16x8 qfB0 = *(const bf16x8*)&Q[(size_t)(qrB+li)*DK +      quad*8];
  bf16x8 qfB1 = *(const bf16x8*)&Q[(size_t)(qrB+li)*DK + 32 + quad*8];

  // prologue: tile g=0 (k0=0) into buf0; issue loads for tile g=1
  bf16x8 kr0 = *(const bf16x8*)&K[(size_t)(sr   )*DK + sc];
  bf16x8 kr1 = *(const bf16x8*)&K[(size_t)(sr+32)*DK + sc];
  bf16x8 vr0 = *(const bf16x8*)&Vt[(size_t)(sr   )*TT + sc];
  bf16x8 vr1 = *(const bf16x8*)&Vt[(size_t)(sr+32)*TT + sc];
  *(bf16x8*)&Kl[0][sr   ][sc] = kr0;
  *(bf16x8*)&Kl[0][sr+32][sc] = kr1;
  *(bf16x8*)&Vl[0][sr   ][sc] = vr0;
  *(bf16x8*)&Vl[0][sr+32][sc] = vr1;
  {
    const int kn = (1 < ntA) ? 64 : 0;         // k0 of tile g=1
    kr0 = *(const bf16x8*)&K[(size_t)(kn+sr   )*DK + sc];
    kr1 = *(const bf16x8*)&K[(size_t)(kn+sr+32)*DK + sc];
    vr0 = *(const bf16x8*)&Vt[(size_t)(sr   )*TT + kn + sc];
    vr1 = *(const bf16x8*)&Vt[(size_t)(sr+32)*TT + kn + sc];
  }

  f32x4 o[4];
  #pragma unroll
  for (int d=0;d<4;d++) o[d] = f32x4{0.f,0.f,0.f,0.f};
  float lp = 0.f;
  int qrow0 = qrA;
  bf16x8 qf0 = qfA0, qf1 = qfA1;
  int cur = 0;

  for (int g = 0; g < 33; g++) {
    __syncthreads();                            // buf[cur] visible; all waves done iter g-1
    const int k0 = ((g < ntA) ? g : (g - ntA)) * 64;
    const bool dg = (g == ntA-1) || (g == 32);  // diagonal tile of current phase

    // S^T = K @ Q^T : A=K-frag, B=Q-frag; C-layout: q=li, key=k0+c*16+quad*4+r
    f32x4 s[4];
    #pragma unroll
    for (int c=0;c<4;c++) {
      bf16x8 kf0 = *(const bf16x8*)&Kl[cur][c*16+li][     quad*8];
      bf16x8 kf1 = *(const bf16x8*)&Kl[cur][c*16+li][32 + quad*8];
      f32x4 t = __builtin_amdgcn_mfma_f32_16x16x32_bf16(kf0, qf0, f32x4{0.f,0.f,0.f,0.f}, 0,0,0);
      s[c]    = __builtin_amdgcn_mfma_f32_16x16x32_bf16(kf1, qf1, t, 0,0,0);
    }
    const int qq = qrow0 + li;
    float p[4][4];
    if (dg) {
      #pragma unroll
      for (int c=0;c<4;c++)
        #pragma unroll
        for (int r=0;r<4;r++){
          int key = k0 + c*16 + quad*4 + r;
          p[c][r] = (key <= qq) ? __expf(s[c][r]) : 0.f;
        }
    } else {
      #pragma unroll
      for (int c=0;c<4;c++)
        #pragma unroll
        for (int r=0;r<4;r++)
          p[c][r] = __expf(s[c][r]);
    }
    #pragma unroll
    for (int c=0;c<4;c++)
      #pragma unroll
      for (int r=0;r<4;r++)
        lp += p[c][r];

    // P^T -> LDS [q][key]: b64 writes, b128 reads (wave-local)
    #pragma unroll
    for (int c=0;c<4;c++) {
      u16x4 w;
      #pragma unroll
      for (int r=0;r<4;r++) w[r] = f2b(p[c][r]);
      *(u16x4*)&Pb[wid][li][c*16 + quad*4] = w;
    }
    __builtin_amdgcn_wave_barrier();
    __asm__ __volatile__("s_waitcnt lgkmcnt(0)");
    bf16x8 pf0 = *(const bf16x8*)&Pb[wid][li][     quad*8];
    bf16x8 pf1 = *(const bf16x8*)&Pb[wid][li][32 + quad*8];

    // O^T += V^T @ P^T
    #pragma unroll
    for (int d=0;d<4;d++){
      bf16x8 vf0 = *(const bf16x8*)&Vl[cur][d*16+li][     quad*8];
      bf16x8 vf1 = *(const bf16x8*)&Vl[cur][d*16+li][32 + quad*8];
      o[d] = __builtin_amdgcn_mfma_f32_16x16x32_bf16(vf0, pf0, o[d], 0,0,0);
      o[d] = __builtin_amdgcn_mfma_f32_16x16x32_bf16(vf1, pf1, o[d], 0,0,0);
    }

    // write next buffer (regs prefetched one iter ago), then issue loads for g+2
    if (g + 1 < 33) {
      *(bf16x8*)&Kl[cur^1][sr   ][sc] = kr0;
      *(bf16x8*)&Kl[cur^1][sr+32][sc] = kr1;
      *(bf16x8*)&Vl[cur^1][sr   ][sc] = vr0;
      *(bf16x8*)&Vl[cur^1][sr+32][sc] = vr1;
      if (g + 2 < 33) {
        const int g2 = g + 2;
        const int kn = ((g2 < ntA) ? g2 : (g2 - ntA)) * 64;
        kr0 = *(const bf16x8*)&K[(size_t)(kn+sr   )*DK + sc];
        kr1 = *(const bf16x8*)&K[(size_t)(kn+sr+32)*DK + sc];
        vr0 = *(const bf16x8*)&Vt[(size_t)(sr   )*TT + kn + sc];
        vr1 = *(const bf16x8*)&Vt[(size_t)(sr+32)*TT + kn + sc];
      }
    }
    cur ^= 1;

    if (g == ntA-1) {                           // finalize phase A, switch to phase B
      float l = lp;
      l += __shfl_xor(l, 16, 64);
      l += __shfl_xor(l, 32, 64);
      float rl = 1.0f / l;
      #pragma unroll
      for (int d=0;d<4;d++){
        u16x4 w;
        #pragma unroll
        for (int r=0;r<4;r++) w[r] = f2b(o[d][r] * rl);
        *(u16x4*)&ctx[(size_t)(b*TT + qrA + li)*DM + h*DK + d*16 + quad*4] = w;
      }
      #pragma unroll
      for (int d=0;d<4;d++) o[d] = f32x4{0.f,0.f,0.f,0.f};
      lp = 0.f;
      qrow0 = qrB; qf0 = qfB0; qf1 = qfB1;
    }
  }

  // finalize phase B
  lp += __shfl_xor(lp, 16, 64);
  lp += __shfl_xor(lp, 32, 64);
  float rl = 1.0f / lp;
  #pragma unroll
  for (int d=0;d<4;d++){
    u16x4 w;
    #pragma unroll
    for (int r=0;r<4;r++) w[r] = f2b(o[d][r] * rl);
    *(u16x4*)&ctx[(size_t)(b*TT + qrB + li)*DM + h*DK + d*16 + quad*4] = w;
  }
}

extern "C" void kernel_launch(void* const* d_in, const int* in_sizes, int n_in,
                              void* d_out, int out_size, void* d_ws, size_t ws_size,
                              hipStream_t stream) {
  const float* q   = (const float*)d_in[0];
  const float* k   = (const float*)d_in[1];
  const float* v   = (const float*)d_in[2];
  // d_in[3]: mask (int32 causal tril) — causality hard-coded in flash kernel
  const float* wq  = (const float*)d_in[4];
  const float* bq  = (const float*)d_in[5];
  const float* wk  = (const float*)d_in[6];
  const float* bk  = (const float*)d_in[7];
  const float* wv  = (const float*)d_in[8];
  const float* bv  = (const float*)d_in[9];
  const float* wo  = (const float*)d_in[10];
  const float* bo  = (const float*)d_in[11];
  float* out = (float*)d_out;

  const size_t SZ = (size_t)BATCH*TT*DM;
  u16* wt  = (u16*)d_ws;                        // 4 x 1024x1024 bf16 = 8 MB
  u16* qb  = wt + (size_t)4*DM*DM;
  u16* kb  = qb + SZ;
  u16* vb  = kb + SZ;
  u16* qh  = vb + SZ;
  u16* kh  = qh + SZ;
  u16* vhT = kh + SZ;
  u16* ctx = qb;                                // alias: qb dead after gemm_qkv

  prep<<<dim3(2048, 1, 7), 256, 0, stream>>>(q, k, v, wq, wk, wv, wo, qb, kb, vb, wt);

  gemm_qkv<<<dim3(4096/128, DM/128, 3), 256, 0, stream>>>(qb, kb, vb, wt, bq, bk, bv, qh, kh, vhT);

  flash<<<dim3(BATCH*NH, 16), 256, 0, stream>>>(qh, kh, vhT, ctx);

  gemm_out64<<<dim3(4096/128, DM/64), 256, 0, stream>>>(ctx, wt + (size_t)3*DM*DM, bo, out);
}